// Round 1
// baseline (197.644 us; speedup 1.0000x reference)
//
#include <hip/hip_runtime.h>

// Involution fused: B=16, C=256, H=W=56, mid=64, GROUPS=16, GROUP_SIZE=16, K=3
// All fp32. Output (16,256,56,56).

#define Cn    256
#define MID   64
#define Hn    56
#define Wn    56
#define HW    3136
#define Bn    16
#define NPIX  (Bn * HW)       // 50176
#define CHW   (Cn * HW)
#define NKK   9
#define NG    16
#define GSZ   16
#define PXT   64              // pixels per block (49 blocks/batch, 784 total)
#define BN_EPS 1e-5f

// async global->LDS: per-lane global src, wave-uniform LDS base + lane*size
#define GLOAD_LDS(src, dst, sz)                                                        \
  __builtin_amdgcn_global_load_lds(                                                    \
      (const __attribute__((address_space(1))) void*)(src),                            \
      (__attribute__((address_space(3))) void*)(dst), (sz), 0, 0)

// ---------------------------------------------------------------------------
// prep: w1f[c*64+o] = w1[o*256+c] * scale[o];  bias1[o] = beta[o]-mean[o]*scale[o]
// ---------------------------------------------------------------------------
__global__ __launch_bounds__(256) void prep_kernel(
    const float* __restrict__ w1,
    const float* __restrict__ gamma,
    const float* __restrict__ beta,
    const float* __restrict__ mean,
    const float* __restrict__ var,
    float* __restrict__ w1f,
    float* __restrict__ bias1) {
  int idx = blockIdx.x * 256 + threadIdx.x;
  if (idx < MID * Cn) {
    int c = idx >> 6;
    int o = idx & 63;
    float scale = gamma[o] / sqrtf(var[o] + BN_EPS);
    w1f[idx] = w1[o * Cn + c] * scale;
  } else if (idx < MID * Cn + MID) {
    int o = idx - MID * Cn;
    float scale = gamma[o] / sqrtf(var[o] + BN_EPS);
    bias1[o] = beta[o] - mean[o] * scale;
  }
}

// ---------------------------------------------------------------------------
// Fused conv1 + conv2 + involution. Block = 64 px, 4 waves.
//
// LDS plan (52 KB total -> 3 blocks/CU, matches the 784-block grid):
//   lt[64][64]   16 KB : conv1 output tile (relu'd), phase-2 input
//   uni[9216]    36 KB : UNION
//     conv1 phase: lx dbuf  = uni[0    .. 2047]  (2 x 16 c x 64 px)
//                  lwt dbuf = uni[2048 .. 4095]  (2 x 16 c x 64 o)
//     phase 2/3  : lw2      = uni[0    .. 9215]  (w2 verbatim, [144][64])
//
// conv1: wave w computes outputs w*16..w*16+15 for all 64 px. x tile AND
// weight slab staged via global_load_lds (double-buffered) -> inner loop is
// pure LDS reads + FMA (weight reads are uniform -> broadcast, conflict-free).
//
// phase 2: per-thread kernel weights a[9] for 4 groups, kept in REGISTERS
// (the old lw LDS buffer was a thread-local round trip). w2 read from LDS.
//
// phase 3: involution per group immediately after its a[9] is ready.
// ---------------------------------------------------------------------------
__global__ __launch_bounds__(256) void fused_kernel(
    const float* __restrict__ x,
    const float* __restrict__ w1f,
    const float* __restrict__ bias1,
    const float* __restrict__ w2,
    const float* __restrict__ b2,
    float* __restrict__ out) {
  __shared__ float lt[MID][PXT];              // 16 KB
  __shared__ __align__(16) float uni[9216];   // 36 KB union

  const int tid = threadIdx.x;
  const int px  = tid & 63;                   // lane id within wave
  const int wvv = tid >> 6;                   // 0..3
  const int wv  = __builtin_amdgcn_readfirstlane(wvv);

  const int px0 = blockIdx.x * PXT;
  const int b   = px0 / HW;
  const int hw0 = px0 - b * HW;
  const float* xb = x + (size_t)b * CHW + hw0;

  // ---- conv1 prologue: stage c-tile 0 into buffer 0 ----
  {
#pragma unroll
    for (int j = 0; j < 4; ++j) {
      const int c = (wv << 2) + j;                      // rows 0..15 split over waves
      GLOAD_LDS(xb + (size_t)c * HW + px, &uni[c * 64], 4);
    }
    GLOAD_LDS(w1f + (wv << 8) + (px << 2), &uni[2048 + (wv << 8)], 16);
  }
  __syncthreads();

  float acc[16];
#pragma unroll
  for (int j = 0; j < 16; ++j) acc[j] = 0.0f;

  for (int k = 0; k < 16; ++k) {
    const int cur = k & 1;
    if (k < 15) {                              // prefetch next c-tile (async)
      const int nb = cur ^ 1;
      const int kb = k + 1;
#pragma unroll
      for (int j = 0; j < 4; ++j) {
        const int c = (wv << 2) + j;
        GLOAD_LDS(xb + (size_t)(kb * 16 + c) * HW + px, &uni[nb * 1024 + c * 64], 4);
      }
      GLOAD_LDS(w1f + kb * 1024 + (wv << 8) + (px << 2),
                &uni[2048 + nb * 1024 + (wv << 8)], 16);
    }
    const float* lx = &uni[cur * 1024];
    const float* lw = &uni[2048 + cur * 1024 + (wv << 4)];
#pragma unroll
    for (int c = 0; c < 16; ++c) {
      const float xv = lx[(c << 6) + px];
      const float4 w40 = *(const float4*)(lw + (c << 6) + 0);
      const float4 w41 = *(const float4*)(lw + (c << 6) + 4);
      const float4 w42 = *(const float4*)(lw + (c << 6) + 8);
      const float4 w43 = *(const float4*)(lw + (c << 6) + 12);
      acc[0]  = fmaf(xv, w40.x, acc[0]);
      acc[1]  = fmaf(xv, w40.y, acc[1]);
      acc[2]  = fmaf(xv, w40.z, acc[2]);
      acc[3]  = fmaf(xv, w40.w, acc[3]);
      acc[4]  = fmaf(xv, w41.x, acc[4]);
      acc[5]  = fmaf(xv, w41.y, acc[5]);
      acc[6]  = fmaf(xv, w41.z, acc[6]);
      acc[7]  = fmaf(xv, w41.w, acc[7]);
      acc[8]  = fmaf(xv, w42.x, acc[8]);
      acc[9]  = fmaf(xv, w42.y, acc[9]);
      acc[10] = fmaf(xv, w42.z, acc[10]);
      acc[11] = fmaf(xv, w42.w, acc[11]);
      acc[12] = fmaf(xv, w43.x, acc[12]);
      acc[13] = fmaf(xv, w43.y, acc[13]);
      acc[14] = fmaf(xv, w43.z, acc[14]);
      acc[15] = fmaf(xv, w43.w, acc[15]);
    }
    __syncthreads();   // drains prefetch (vmcnt) + guards dbuf swap
  }

  // ---- conv1 epilogue: bias + relu -> lt. All uni reads finished at the
  //      last barrier, so w2 staging can overwrite uni concurrently. ----
#pragma unroll
  for (int j = 0; j < 16; ++j) {
    const int o = (wv << 4) + j;
    lt[o][px] = fmaxf(acc[j] + bias1[o], 0.0f);
  }
#pragma unroll
  for (int i = 0; i < 9; ++i) {                // 36 KB w2, linear copy
    const int r = wv * 9 + i;                  // 0..35, 256 floats each
    GLOAD_LDS(w2 + ((size_t)r << 8) + (px << 2), &uni[r << 8], 16);
  }
  __syncthreads();

  // ---- phase 2+3 per group: conv2 weights in registers, then involution ----
  const int hw = hw0 + px;
  const int h  = hw / Wn;
  const int w  = hw - h * Wn;

  int off[NKK];
  unsigned vmask = 0;
#pragma unroll
  for (int kk = 0; kk < NKK; ++kk) {
    const int di  = kk / 3 - 1;
    const int dj  = kk % 3 - 1;
    const int h2  = h + di;
    const int w2v = w + dj;
    const bool valid = ((unsigned)h2 < (unsigned)Hn) && ((unsigned)w2v < (unsigned)Wn);
    off[kk] = valid ? (h2 * Wn + w2v) : hw;
    vmask |= (valid ? 1u : 0u) << kk;
  }

  const float* xg = x + (size_t)b * CHW;
  float* ob = out + (size_t)b * CHW + hw;

  for (int gi = 0; gi < 4; ++gi) {
    const int g = wv + (gi << 2);              // wave-uniform group id
    float a[NKK];
#pragma unroll
    for (int kk = 0; kk < NKK; ++kk) a[kk] = b2[g * NKK + kk];

#pragma unroll 4
    for (int o4 = 0; o4 < MID; o4 += 4) {
      const float t0 = lt[o4 + 0][px];
      const float t1 = lt[o4 + 1][px];
      const float t2 = lt[o4 + 2][px];
      const float t3 = lt[o4 + 3][px];
#pragma unroll
      for (int kk = 0; kk < NKK; ++kk) {
        const float4 w4 = *(const float4*)&uni[((g * NKK + kk) << 6) + o4];
        a[kk] = fmaf(t3, w4.w, fmaf(t2, w4.z, fmaf(t1, w4.y, fmaf(t0, w4.x, a[kk]))));
      }
    }

    float wk[NKK];
#pragma unroll
    for (int kk = 0; kk < NKK; ++kk)
      wk[kk] = ((vmask >> kk) & 1u) ? a[kk] : 0.0f;

    const float* xc0 = xg + (size_t)(g * GSZ) * HW;
#pragma unroll 4
    for (int cc = 0; cc < GSZ; ++cc) {
      const float* xc = xc0 + (size_t)cc * HW;
      float s = 0.0f;
#pragma unroll
      for (int kk = 0; kk < NKK; ++kk)
        s = fmaf(wk[kk], xc[off[kk]], s);
      ob[(size_t)(g * GSZ + cc) * HW] = s;
    }
  }
}

// ---------------------------------------------------------------------------
extern "C" void kernel_launch(void* const* d_in, const int* in_sizes, int n_in,
                              void* d_out, int out_size, void* d_ws, size_t ws_size,
                              hipStream_t stream) {
  const float* x     = (const float*)d_in[0];
  const float* w1    = (const float*)d_in[1];
  const float* gamma = (const float*)d_in[2];
  const float* beta  = (const float*)d_in[3];
  const float* mean  = (const float*)d_in[4];
  const float* var   = (const float*)d_in[5];
  const float* w2    = (const float*)d_in[6];
  const float* b2    = (const float*)d_in[7];
  float* out = (float*)d_out;

  // workspace: w1f (64 KB) | bias1 (256 B)   (t eliminated by fusion)
  char* ws = (char*)d_ws;
  float* w1f   = (float*)ws;
  float* bias1 = (float*)(ws + (size_t)MID * Cn * 4);

  prep_kernel<<<(MID * Cn + MID + 255) / 256, 256, 0, stream>>>(
      w1, gamma, beta, mean, var, w1f, bias1);
  fused_kernel<<<NPIX / PXT, 256, 0, stream>>>(x, w1f, bias1, w2, b2, out);
}

// Round 2
// 176.434 us; speedup vs baseline: 1.1202x; 1.1202x over previous
//
#include <hip/hip_runtime.h>

// Involution: B=16, C=256, H=W=56, mid=64, GROUPS=16, GROUP_SIZE=16, K=3 (KK=9)
// All fp32. Output (16,256,56,56).
//
// Structure (3 dispatches; ~80us of bench time is fixed harness overhead):
//   prep      : fold BN into w1 (transposed) + bias           (~3 us)
//   conv1     : 1x1 conv x->t, LDS double-buffered staging    (~10 us)
//   conv2_inv : per-pixel kernels (regs) + involution,
//               grid = px-chunks x group-quads for occupancy  (target ~35 us)

#define Cn    256
#define MID   64
#define Hn    56
#define Wn    56
#define HW    3136
#define Bn    16
#define NPIX  (Bn * HW)       // 50176
#define CHW   (Cn * HW)
#define NKK   9
#define NG    16
#define GSZ   16
#define PXT   64              // pixels per chunk (49 chunks/batch, 784 total)
#define BN_EPS 1e-5f

// async global->LDS: per-lane global src, wave-uniform LDS base + lane*size
#define GLOAD_LDS(src, dst, sz)                                                        \
  __builtin_amdgcn_global_load_lds(                                                    \
      (const __attribute__((address_space(1))) void*)(src),                            \
      (__attribute__((address_space(3))) void*)(dst), (sz), 0, 0)

// ---------------------------------------------------------------------------
// prep: w1f[c*64+o] = w1[o*256+c] * scale[o];  bias1[o] = beta[o]-mean[o]*scale[o]
// ---------------------------------------------------------------------------
__global__ __launch_bounds__(256) void prep_kernel(
    const float* __restrict__ w1,
    const float* __restrict__ gamma,
    const float* __restrict__ beta,
    const float* __restrict__ mean,
    const float* __restrict__ var,
    float* __restrict__ w1f,
    float* __restrict__ bias1) {
  int idx = blockIdx.x * 256 + threadIdx.x;
  if (idx < MID * Cn) {
    int c = idx >> 6;
    int o = idx & 63;
    float scale = gamma[o] / sqrtf(var[o] + BN_EPS);
    w1f[idx] = w1[o * Cn + c] * scale;
  } else if (idx < MID * Cn + MID) {
    int o = idx - MID * Cn;
    float scale = gamma[o] / sqrtf(var[o] + BN_EPS);
    bias1[o] = beta[o] - mean[o] * scale;
  }
}

// ---------------------------------------------------------------------------
// conv1: t[o][gp] = relu(bias1[o] + sum_c x[b,c,hw] * w1f[c][o])
// Block = 64 px, 4 waves; wave w computes outputs w*16..w*16+15.
// x tile AND weight slab staged via global_load_lds, double-buffered.
// LDS 16 KB -> occupancy not LDS-limited (grid-limited at 784 blocks).
// ---------------------------------------------------------------------------
__global__ __launch_bounds__(256) void conv1_kernel(
    const float* __restrict__ x,
    const float* __restrict__ w1f,
    const float* __restrict__ bias1,
    float* __restrict__ t) {
  __shared__ __align__(16) float sb[4096];   // x dbuf [0..2047], w dbuf [2048..4095]

  const int tid = threadIdx.x;
  const int px  = tid & 63;
  const int wvv = tid >> 6;                             // 0..3
  const int wv  = __builtin_amdgcn_readfirstlane(wvv);

  const int px0 = blockIdx.x * PXT;
  const int b   = px0 / HW;
  const int hw0 = px0 - b * HW;
  const float* xb = x + (size_t)b * CHW + hw0;

  // prologue: stage c-tile 0 into buffer 0
#pragma unroll
  for (int j = 0; j < 4; ++j) {
    const int c = (wv << 2) + j;
    GLOAD_LDS(xb + (size_t)c * HW + px, &sb[c * 64], 4);
  }
  GLOAD_LDS(w1f + (wv << 8) + (px << 2), &sb[2048 + (wv << 8)], 16);
  __syncthreads();

  float acc[16];
#pragma unroll
  for (int j = 0; j < 16; ++j) acc[j] = 0.0f;

  for (int k = 0; k < 16; ++k) {
    const int cur = k & 1;
    if (k < 15) {                            // async prefetch of next c-tile
      const int nb = cur ^ 1;
      const int kb = k + 1;
#pragma unroll
      for (int j = 0; j < 4; ++j) {
        const int c = (wv << 2) + j;
        GLOAD_LDS(xb + (size_t)(kb * 16 + c) * HW + px, &sb[nb * 1024 + c * 64], 4);
      }
      GLOAD_LDS(w1f + kb * 1024 + (wv << 8) + (px << 2),
                &sb[2048 + nb * 1024 + (wv << 8)], 16);
    }
    const float* lx = &sb[cur * 1024];
    const float* lw = &sb[2048 + cur * 1024 + (wv << 4)];
#pragma unroll
    for (int c = 0; c < 16; ++c) {
      const float xv = lx[(c << 6) + px];
      const float4 w40 = *(const float4*)(lw + (c << 6) + 0);
      const float4 w41 = *(const float4*)(lw + (c << 6) + 4);
      const float4 w42 = *(const float4*)(lw + (c << 6) + 8);
      const float4 w43 = *(const float4*)(lw + (c << 6) + 12);
      acc[0]  = fmaf(xv, w40.x, acc[0]);
      acc[1]  = fmaf(xv, w40.y, acc[1]);
      acc[2]  = fmaf(xv, w40.z, acc[2]);
      acc[3]  = fmaf(xv, w40.w, acc[3]);
      acc[4]  = fmaf(xv, w41.x, acc[4]);
      acc[5]  = fmaf(xv, w41.y, acc[5]);
      acc[6]  = fmaf(xv, w41.z, acc[6]);
      acc[7]  = fmaf(xv, w41.w, acc[7]);
      acc[8]  = fmaf(xv, w42.x, acc[8]);
      acc[9]  = fmaf(xv, w42.y, acc[9]);
      acc[10] = fmaf(xv, w42.z, acc[10]);
      acc[11] = fmaf(xv, w42.w, acc[11]);
      acc[12] = fmaf(xv, w43.x, acc[12]);
      acc[13] = fmaf(xv, w43.y, acc[13]);
      acc[14] = fmaf(xv, w43.z, acc[14]);
      acc[15] = fmaf(xv, w43.w, acc[15]);
    }
    __syncthreads();   // drains prefetch (vmcnt) + guards dbuf swap
  }

#pragma unroll
  for (int j = 0; j < 16; ++j) {
    const int o = (wv << 4) + j;
    t[(size_t)o * NPIX + px0 + px] = fmaxf(acc[j] + bias1[o], 0.0f);
  }
}

// ---------------------------------------------------------------------------
// conv2 + involution. Block = 64 px x ONE group-quad (4 groups).
// grid = 784 * 4 = 3136 blocks -> 12.25 blocks/CU; LDS 25.3 KB -> 6 blocks/CU.
// Wave wv owns group gq*4+wv exclusively:
//   - conv2 weights a[9] computed in registers (t tile + w2 from LDS)
//   - involution over the group's 16 channels (9 coalesced taps each)
// ---------------------------------------------------------------------------
__global__ __launch_bounds__(256) void conv2_inv_kernel(
    const float* __restrict__ x,
    const float* __restrict__ t,
    const float* __restrict__ w2,
    const float* __restrict__ b2,
    float* __restrict__ out) {
  __shared__ float lt[MID][PXT];                        // 16 KB
  __shared__ __align__(16) float lw2f[4 * NKK * MID];   // 9 KB (quad's w2 rows)

  const int tid = threadIdx.x;
  const int px  = tid & 63;
  const int wvv = tid >> 6;                             // 0..3
  const int wv  = __builtin_amdgcn_readfirstlane(wvv);

  const int bid = blockIdx.x;
  const int pc  = bid >> 2;            // pixel chunk 0..783
  const int gq  = bid & 3;             // group quad 0..3
  const int g   = (gq << 2) + wv;      // this wave's group, wave-uniform

  const int px0 = pc * PXT;
  const int b   = px0 / HW;
  const int hw0 = px0 - b * HW;

  // ---- stage t tile (64 rows x 64 px) + this quad's w2 (2304 floats) ----
#pragma unroll
  for (int j = 0; j < 16; ++j) {
    const int o = (wv << 4) + j;
    GLOAD_LDS(t + (size_t)o * NPIX + px0 + px, &lt[o][0], 4);
  }
  // w2 rows gq*36 .. gq*36+35 are contiguous: linear copy in 1 KB chunks
  for (int ch = wv; ch < 9; ch += 4) {
    GLOAD_LDS(w2 + (size_t)gq * (4 * NKK * MID) + (ch << 8) + (px << 2),
              &lw2f[ch << 8], 16);
  }
  __syncthreads();

  // ---- conv2: per-pixel kernel weights for group g, in registers ----
  float a[NKK];
#pragma unroll
  for (int kk = 0; kk < NKK; ++kk) a[kk] = b2[g * NKK + kk];
  const float* wq = &lw2f[wv * (NKK * MID)];   // wave-uniform -> LDS broadcast
#pragma unroll 4
  for (int o4 = 0; o4 < MID; o4 += 4) {
    const float t0 = lt[o4 + 0][px];
    const float t1 = lt[o4 + 1][px];
    const float t2 = lt[o4 + 2][px];
    const float t3 = lt[o4 + 3][px];
#pragma unroll
    for (int kk = 0; kk < NKK; ++kk) {
      const float4 w4 = *(const float4*)&wq[(kk << 6) + o4];
      a[kk] = fmaf(t3, w4.w, fmaf(t2, w4.z, fmaf(t1, w4.y, fmaf(t0, w4.x, a[kk]))));
    }
  }

  // ---- involution over this group's 16 channels ----
  const int hw = hw0 + px;
  const int h  = hw / Wn;
  const int w  = hw - h * Wn;

  int off[NKK];
  unsigned vmask = 0;
#pragma unroll
  for (int kk = 0; kk < NKK; ++kk) {
    const int di  = kk / 3 - 1;
    const int dj  = kk % 3 - 1;
    const int h2  = h + di;
    const int w2v = w + dj;
    const bool valid = ((unsigned)h2 < (unsigned)Hn) && ((unsigned)w2v < (unsigned)Wn);
    off[kk] = valid ? (h2 * Wn + w2v) : hw;
    vmask |= (valid ? 1u : 0u) << kk;
  }

  float wk[NKK];
#pragma unroll
  for (int kk = 0; kk < NKK; ++kk)
    wk[kk] = ((vmask >> kk) & 1u) ? a[kk] : 0.0f;

  const float* xc = x + (size_t)b * CHW + (size_t)(g * GSZ) * HW;
  float* ob = out + (size_t)b * CHW + (size_t)(g * GSZ) * HW + hw;
#pragma unroll 4
  for (int cc = 0; cc < GSZ; ++cc) {
    const float* xp = xc + (size_t)cc * HW;
    float s0 = wk[0] * xp[off[0]];
    float s1 = wk[1] * xp[off[1]];
    float s2 = wk[2] * xp[off[2]];
    s0 = fmaf(wk[3], xp[off[3]], s0);
    s1 = fmaf(wk[4], xp[off[4]], s1);
    s2 = fmaf(wk[5], xp[off[5]], s2);
    s0 = fmaf(wk[6], xp[off[6]], s0);
    s1 = fmaf(wk[7], xp[off[7]], s1);
    s2 = fmaf(wk[8], xp[off[8]], s2);
    ob[(size_t)cc * HW] = s0 + s1 + s2;
  }
}

// ---------------------------------------------------------------------------
extern "C" void kernel_launch(void* const* d_in, const int* in_sizes, int n_in,
                              void* d_out, int out_size, void* d_ws, size_t ws_size,
                              hipStream_t stream) {
  const float* x     = (const float*)d_in[0];
  const float* w1    = (const float*)d_in[1];
  const float* gamma = (const float*)d_in[2];
  const float* beta  = (const float*)d_in[3];
  const float* mean  = (const float*)d_in[4];
  const float* var   = (const float*)d_in[5];
  const float* w2    = (const float*)d_in[6];
  const float* b2    = (const float*)d_in[7];
  float* out = (float*)d_out;

  // workspace: t (64 x 50176 fp32 = 12.85 MB) | w1f (64 KB) | bias1 (256 B)
  char* ws = (char*)d_ws;
  float* t     = (float*)ws;
  float* w1f   = (float*)(ws + (size_t)MID * NPIX * 4);
  float* bias1 = (float*)(ws + (size_t)MID * NPIX * 4 + (size_t)MID * Cn * 4);

  prep_kernel<<<(MID * Cn + MID + 255) / 256, 256, 0, stream>>>(
      w1, gamma, beta, mean, var, w1f, bias1);
  conv1_kernel<<<NPIX / PXT, 256, 0, stream>>>(x, w1f, bias1, t);
  conv2_inv_kernel<<<NPIX / PXT * 4, 256, 0, stream>>>(x, t, w2, b2, out);
}

// Round 3
// 161.943 us; speedup vs baseline: 1.2205x; 1.0895x over previous
//
#include <hip/hip_runtime.h>

// Involution: B=16, C=256, H=W=56, mid=64, GROUPS=16, GROUP_SIZE=16, K=3 (KK=9)
// All fp32. Output (16,256,56,56).
//
// Key idea this revision: wave-UNIFORM operands (conv1 weights, conv2 w2 rows)
// move off the LDS pipe onto the SCALAR pipe (s_load via readfirstlane-uniform
// addresses on const __restrict__ args). LDS carries only per-lane data (x, t).

#define Cn    256
#define MID   64
#define Hn    56
#define Wn    56
#define HW    3136
#define Bn    16
#define NPIX  (Bn * HW)       // 50176
#define CHW   (Cn * HW)
#define NKK   9
#define NG    16
#define GSZ   16
#define PXT   64              // pixels per chunk (49 chunks/batch, 784 total)
#define BN_EPS 1e-5f

// async global->LDS: per-lane global src, wave-uniform LDS base + lane*size
#define GLOAD_LDS(src, dst, sz)                                                        \
  __builtin_amdgcn_global_load_lds(                                                    \
      (const __attribute__((address_space(1))) void*)(src),                            \
      (__attribute__((address_space(3))) void*)(dst), (sz), 0, 0)

// ---------------------------------------------------------------------------
// prep: w1f[c*64+o] = w1[o*256+c] * scale[o];  bias1[o] = beta[o]-mean[o]*scale[o]
// ---------------------------------------------------------------------------
__global__ __launch_bounds__(256) void prep_kernel(
    const float* __restrict__ w1,
    const float* __restrict__ gamma,
    const float* __restrict__ beta,
    const float* __restrict__ mean,
    const float* __restrict__ var,
    float* __restrict__ w1f,
    float* __restrict__ bias1) {
  int idx = blockIdx.x * 256 + threadIdx.x;
  if (idx < MID * Cn) {
    int c = idx >> 6;
    int o = idx & 63;
    float scale = gamma[o] / sqrtf(var[o] + BN_EPS);
    w1f[idx] = w1[o * Cn + c] * scale;
  } else if (idx < MID * Cn + MID) {
    int o = idx - MID * Cn;
    float scale = gamma[o] / sqrtf(var[o] + BN_EPS);
    bias1[o] = beta[o] - mean[o] * scale;
  }
}

// ---------------------------------------------------------------------------
// conv1: t[o][gp] = relu(bias1[o] + sum_c x[b,c,hw] * w1f[c][o])
// Block = 64 px x 32 outputs (OSPLIT=2 -> grid 1568 for occupancy).
// Wave wv computes outputs oh*32 + wv*8 .. +7 for all 64 px.
//  - x tile: double-buffered LDS via ONE width-16 global_load_lds per wave
//    (lane i covers row wv*4+(i>>4), cols (i&15)*4.. of the 16x64 tile).
//  - weights: wave-uniform s_load from global (scalar pipe, zero LDS traffic).
// LDS = 8 KB -> occupancy grid-limited (~6 blocks/CU), not LDS-limited.
// ---------------------------------------------------------------------------
__global__ __launch_bounds__(256) void conv1_kernel(
    const float* __restrict__ x,
    const float* __restrict__ w1f,
    const float* __restrict__ bias1,
    float* __restrict__ t) {
  __shared__ __align__(16) float lx[2][16][PXT];   // 8 KB

  const int tid = threadIdx.x;
  const int px  = tid & 63;
  const int wv  = __builtin_amdgcn_readfirstlane(tid >> 6);   // 0..3

  const int bid = blockIdx.x;
  const int pc  = bid >> 1;            // pixel chunk 0..783
  const int oh  = bid & 1;             // output half 0..1
  const int px0 = pc * PXT;
  const int b   = px0 / HW;
  const int hw0 = px0 - b * HW;
  const float* xb = x + (size_t)b * CHW + hw0;

  const int rsub = px >> 4;            // 0..3  (row within wave's 4-row slab)
  const int csub = (px & 15) << 2;     // 0,4,..,60 (float col)

  // prologue: stage c-tile 0 into buffer 0 (one width-16 gload per wave)
  GLOAD_LDS(xb + (size_t)((wv << 2) + rsub) * HW + csub, &lx[0][wv << 2][0], 16);
  __syncthreads();

  float acc[8];
#pragma unroll
  for (int j = 0; j < 8; ++j) acc[j] = 0.0f;

  for (int k = 0; k < 16; ++k) {
    const int cur = k & 1;
    if (k < 15) {                      // async prefetch of next c-tile
      GLOAD_LDS(xb + (size_t)((k + 1) * 16 + (wv << 2) + rsub) * HW + csub,
                &lx[cur ^ 1][wv << 2][0], 16);
    }
#pragma unroll
    for (int c = 0; c < 16; ++c) {
      const float xv = lx[cur][c][px];
      // wave-uniform weight row -> scalar loads (s_load_dwordx4 x2)
      const float* wr = w1f + (((k << 4) + c) << 6) + (oh << 5) + (wv << 3);
      const float4 wa = *(const float4*)(wr + 0);
      const float4 wb = *(const float4*)(wr + 4);
      acc[0] = fmaf(xv, wa.x, acc[0]);
      acc[1] = fmaf(xv, wa.y, acc[1]);
      acc[2] = fmaf(xv, wa.z, acc[2]);
      acc[3] = fmaf(xv, wa.w, acc[3]);
      acc[4] = fmaf(xv, wb.x, acc[4]);
      acc[5] = fmaf(xv, wb.y, acc[5]);
      acc[6] = fmaf(xv, wb.z, acc[6]);
      acc[7] = fmaf(xv, wb.w, acc[7]);
    }
    __syncthreads();   // drains prefetch (vmcnt) + guards dbuf swap
  }

#pragma unroll
  for (int j = 0; j < 8; ++j) {
    const int o = (oh << 5) + (wv << 3) + j;
    t[(size_t)o * NPIX + px0 + px] = fmaxf(acc[j] + bias1[o], 0.0f);
  }
}

// ---------------------------------------------------------------------------
// conv2 + involution. Block = 64 px x ONE group-quad (4 groups), grid 3136.
// Wave wv owns group gq*4+wv exclusively:
//   - t tile (64x64) in LDS, staged via width-16 gloads (4 per wave)
//   - w2 rows + b2 via wave-uniform s_load (scalar pipe)
//   - per-pixel kernel weights a[9] entirely in registers
//   - involution over the group's 16 channels (9 coalesced taps each)
// LDS = 16 KB -> 8 blocks/CU resident (wave-slot-limited), grid 12.25/CU.
// ---------------------------------------------------------------------------
__global__ __launch_bounds__(256) void conv2_inv_kernel(
    const float* __restrict__ x,
    const float* __restrict__ t,
    const float* __restrict__ w2,
    const float* __restrict__ b2,
    float* __restrict__ out) {
  __shared__ __align__(16) float lt[MID][PXT];          // 16 KB

  const int tid = threadIdx.x;
  const int px  = tid & 63;
  const int wv  = __builtin_amdgcn_readfirstlane(tid >> 6);   // 0..3

  const int bid = blockIdx.x;
  const int pc  = bid >> 2;            // pixel chunk 0..783
  const int gq  = bid & 3;             // group quad 0..3
  const int g   = (gq << 2) + wv;      // this wave's group, wave-uniform

  const int px0 = pc * PXT;
  const int b   = px0 / HW;
  const int hw0 = px0 - b * HW;

  const int rsub = px >> 4;
  const int csub = (px & 15) << 2;

  // ---- stage t tile: wave wv covers rows wv*16 .. wv*16+15 ----
#pragma unroll
  for (int j = 0; j < 4; ++j) {
    const int r0 = (wv << 4) + (j << 2);
    GLOAD_LDS(t + (size_t)(r0 + rsub) * NPIX + px0 + csub, &lt[r0][0], 16);
  }
  __syncthreads();

  // ---- conv2: per-pixel kernel weights for group g, in registers ----
  float a[NKK];
#pragma unroll
  for (int kk = 0; kk < NKK; ++kk) a[kk] = b2[g * NKK + kk];   // uniform s_load

  const float* wg = w2 + (size_t)g * (NKK * MID);              // uniform base
#pragma unroll 4
  for (int o4 = 0; o4 < MID; o4 += 4) {
    const float t0 = lt[o4 + 0][px];
    const float t1 = lt[o4 + 1][px];
    const float t2 = lt[o4 + 2][px];
    const float t3 = lt[o4 + 3][px];
#pragma unroll
    for (int kk = 0; kk < NKK; ++kk) {
      // wave-uniform -> s_load_dwordx4 on scalar pipe
      const float4 w4 = *(const float4*)(wg + (kk << 6) + o4);
      a[kk] = fmaf(t3, w4.w, fmaf(t2, w4.z, fmaf(t1, w4.y, fmaf(t0, w4.x, a[kk]))));
    }
  }

  // ---- involution over this group's 16 channels ----
  const int hw = hw0 + px;
  const int h  = hw / Wn;
  const int w  = hw - h * Wn;

  int off[NKK];
  unsigned vmask = 0;
#pragma unroll
  for (int kk = 0; kk < NKK; ++kk) {
    const int di  = kk / 3 - 1;
    const int dj  = kk % 3 - 1;
    const int h2  = h + di;
    const int w2v = w + dj;
    const bool valid = ((unsigned)h2 < (unsigned)Hn) && ((unsigned)w2v < (unsigned)Wn);
    off[kk] = valid ? (h2 * Wn + w2v) : hw;
    vmask |= (valid ? 1u : 0u) << kk;
  }

  float wk[NKK];
#pragma unroll
  for (int kk = 0; kk < NKK; ++kk)
    wk[kk] = ((vmask >> kk) & 1u) ? a[kk] : 0.0f;

  const float* xc = x + (size_t)b * CHW + (size_t)(g * GSZ) * HW;
  float* ob = out + (size_t)b * CHW + (size_t)(g * GSZ) * HW + hw;
#pragma unroll 4
  for (int cc = 0; cc < GSZ; ++cc) {
    const float* xp = xc + (size_t)cc * HW;
    float s0 = wk[0] * xp[off[0]];
    float s1 = wk[1] * xp[off[1]];
    float s2 = wk[2] * xp[off[2]];
    s0 = fmaf(wk[3], xp[off[3]], s0);
    s1 = fmaf(wk[4], xp[off[4]], s1);
    s2 = fmaf(wk[5], xp[off[5]], s2);
    s0 = fmaf(wk[6], xp[off[6]], s0);
    s1 = fmaf(wk[7], xp[off[7]], s1);
    s2 = fmaf(wk[8], xp[off[8]], s2);
    ob[(size_t)cc * HW] = s0 + s1 + s2;
  }
}

// ---------------------------------------------------------------------------
extern "C" void kernel_launch(void* const* d_in, const int* in_sizes, int n_in,
                              void* d_out, int out_size, void* d_ws, size_t ws_size,
                              hipStream_t stream) {
  const float* x     = (const float*)d_in[0];
  const float* w1    = (const float*)d_in[1];
  const float* gamma = (const float*)d_in[2];
  const float* beta  = (const float*)d_in[3];
  const float* mean  = (const float*)d_in[4];
  const float* var   = (const float*)d_in[5];
  const float* w2    = (const float*)d_in[6];
  const float* b2    = (const float*)d_in[7];
  float* out = (float*)d_out;

  // workspace: t (64 x 50176 fp32 = 12.85 MB) | w1f (64 KB) | bias1 (256 B)
  char* ws = (char*)d_ws;
  float* t     = (float*)ws;
  float* w1f   = (float*)(ws + (size_t)MID * NPIX * 4);
  float* bias1 = (float*)(ws + (size_t)MID * NPIX * 4 + (size_t)MID * Cn * 4);

  prep_kernel<<<(MID * Cn + MID + 255) / 256, 256, 0, stream>>>(
      w1, gamma, beta, mean, var, w1f, bias1);
  conv1_kernel<<<NPIX / PXT * 2, 256, 0, stream>>>(x, w1f, bias1, t);
  conv2_inv_kernel<<<NPIX / PXT * 4, 256, 0, stream>>>(x, t, w2, b2, out);
}